// Round 21
// baseline (256.669 us; speedup 1.0000x reference)
//
#include <hip/hip_runtime.h>
#include <hip/hip_bf16.h>

#define NN 10000
#define EE 160000
#define FF 128
#define UU 128
#define HH 8
#define BN_EPS 1e-3f

typedef __attribute__((ext_vector_type(8))) short bf16x8;
typedef __attribute__((ext_vector_type(8))) unsigned short u16x8;
typedef __attribute__((ext_vector_type(4))) unsigned short u16x4;
typedef __attribute__((ext_vector_type(4))) unsigned int u32x4;
typedef __attribute__((ext_vector_type(4))) float f32x4;
typedef __attribute__((ext_vector_type(2))) float f32x2;

static __device__ __forceinline__ unsigned short f2bf(float f) {
    unsigned u = __float_as_uint(f);
    u += 0x7fffu + ((u >> 16) & 1u);
    return (unsigned short)(u >> 16);
}
static __device__ __forceinline__ float bf2f(unsigned short b) {
    return __uint_as_float((unsigned)b << 16);
}

// ---------------- fused prep: node f2bf + all weight transposes (one launch) ----------------
__global__ void k_prep(const float* __restrict__ node, unsigned short* __restrict__ node_bf,
                       const float* __restrict__ We, unsigned short* __restrict__ WtE,
                       const float* __restrict__ Wn, unsigned short* __restrict__ WnT,
                       const float* __restrict__ Watt, unsigned short* __restrict__ WtA,
                       const float* __restrict__ Wk, const float* __restrict__ Wr,
                       unsigned short* __restrict__ WcT) {
    int b = blockIdx.x, t = threadIdx.x;
    if (b < 1250) {
        int i = b * 256 + t;
        float4 v = reinterpret_cast<const float4*>(node)[i];
        ushort4 o;
        o.x = f2bf(v.x); o.y = f2bf(v.y); o.z = f2bf(v.z); o.w = f2bf(v.w);
        reinterpret_cast<ushort4*>(node_bf)[i] = o;
    } else if (b < 1442) {
        int i = (b - 1250) * 256 + t;                // 3*128*128
        int s = i >> 14, rem = i & 16383, u = rem >> 7, k = rem & 127;
        WtE[i] = f2bf(We[(s * 128 + k) * 128 + u]);
    } else if (b < 1506) {
        int i = (b - 1442) * 256 + t;                // 128*128
        int k = i >> 7, u = i & 127;
        WnT[u * 128 + k] = f2bf(Wn[i]);
    } else if (b < 2018) {
        int i = (b - 1506) * 256 + t;                // 8*128*128
        int h = i >> 14, rem = i & 16383, f = rem >> 7, u = rem & 127;
        WtA[h * 16384 + u * 128 + f] = f2bf(Watt[i]);
    } else {
        int i = (b - 2018) * 256 + t;                // 512*256
        int c = i >> 8, k = i & 255;
        float v;
        if (c < 256)       v = (k < 128) ? Wk[k * 384 + c] : Wr[(k - 128) * 384 + c];
        else if (c < 384)  v = (k < 128) ? Wk[k * 384 + c] : 0.f;
        else               v = (k < 128) ? 0.f : Wr[(k - 128) * 384 + (c - 128)];
        WcT[c * 256 + k] = f2bf(v);
    }
}

// ---------------- CSR construction ----------------
__global__ void k_hist(const int* __restrict__ eidx, int* __restrict__ cnt, int E) {
    int e = blockIdx.x * 256 + threadIdx.x;
    if (e < E) atomicAdd(&cnt[eidx[2 * e]], 1);   // dst = eidx[e][0]
}

__global__ void k_scan(const int* __restrict__ cnt, int* __restrict__ off,
                       int* __restrict__ cursor, int N) {
    __shared__ int wpre[16];
    __shared__ int runsh;
    int t = threadIdx.x, lane = t & 63, wv = t >> 6;
    if (t == 0) { off[0] = 0; runsh = 0; }
    __syncthreads();
    for (int base = 0; base < N; base += 1024) {
        int x = (base + t < N) ? cnt[base + t] : 0;
        int s = x;
#pragma unroll
        for (int o = 1; o < 64; o <<= 1) {
            int v = __shfl_up(s, o, 64);
            if (lane >= o) s += v;
        }
        if (lane == 63) wpre[wv] = s;
        __syncthreads();
        if (t == 0) {
            int acc = runsh;
#pragma unroll
            for (int i = 0; i < 16; ++i) { int tmp = wpre[i]; wpre[i] = acc; acc += tmp; }
            runsh = acc;
        }
        __syncthreads();
        int inc = s + wpre[wv];
        if (base + t < N) {
            off[base + t + 1] = inc;
            cursor[base + t] = inc - x;
        }
        __syncthreads();
    }
}

// scatter: elist[p]=e and inverse map pos[e]=p
__global__ void k_scatter(const int* __restrict__ eidx, int* __restrict__ cursor,
                          int* __restrict__ elist, int* __restrict__ pos, int E) {
    int e = blockIdx.x * 256 + threadIdx.x;
    if (e < E) {
        int d = eidx[2 * e];
        int p = atomicAdd(&cursor[d], 1);
        elist[p] = e;
        pos[e] = p;
    }
}

// ---------------- z (fp8 e4m3, (N,U,H)) = node @ W_att + b_att; fused s_src/s_dst ----------------
__global__ void __launch_bounds__(256) k_z8(
        const unsigned short* __restrict__ node_bf, const unsigned short* __restrict__ WtA,
        const float* __restrict__ batt, const float* __restrict__ aatt,
        unsigned char* __restrict__ zt8, float* __restrict__ s_src, float* __restrict__ s_dst) {
    __shared__ unsigned short lds[16 * 1032];
    int n0 = blockIdx.x * 16;
    int t = threadIdx.x;
    {
        int r = t >> 4, c = t & 15;
        *reinterpret_cast<uint4*>(&lds[r * 136 + c * 8]) =
            *reinterpret_cast<const uint4*>(node_bf + (size_t)(n0 + r) * 128 + c * 8);
    }
    __syncthreads();

    int wid = t >> 6, lane = t & 63;
    int lr = lane & 15, lg = lane >> 4;

    f32x4 acc[2][8];
#pragma unroll
    for (int hh = 0; hh < 2; ++hh)
#pragma unroll
        for (int nt = 0; nt < 8; ++nt) acc[hh][nt] = (f32x4){0.f, 0.f, 0.f, 0.f};

#pragma unroll
    for (int ks = 0; ks < 4; ++ks) {
        int kb = ks * 32 + lg * 8;
        bf16x8 a = *reinterpret_cast<const bf16x8*>(&lds[lr * 136 + kb]);
#pragma unroll
        for (int hh = 0; hh < 2; ++hh) {
            const unsigned short* Wh = WtA + (size_t)(wid * 2 + hh) * 16384;
#pragma unroll
            for (int nt = 0; nt < 8; ++nt) {
                bf16x8 b = *reinterpret_cast<const bf16x8*>(Wh + (size_t)(nt * 16 + lr) * 128 + kb);
                acc[hh][nt] = __builtin_amdgcn_mfma_f32_16x16x32_bf16(a, b, acc[hh][nt], 0, 0, 0);
            }
        }
    }

    __syncthreads();                      // A reads done; reuse lds as fp8 C, row stride 520 u16
    int head0 = wid * 2, head1 = wid * 2 + 1;
    float ps[2][4], pd[2][4];
#pragma unroll
    for (int hh = 0; hh < 2; ++hh)
#pragma unroll
        for (int r = 0; r < 4; ++r) { ps[hh][r] = 0.f; pd[hh][r] = 0.f; }

#pragma unroll
    for (int nt = 0; nt < 8; ++nt) {
        int col = nt * 16 + lr;
        float b0 = batt[head0 * 128 + col], b1 = batt[head1 * 128 + col];
        float as0 = aatt[head0 * 384 + col], ad0 = aatt[head0 * 384 + 128 + col];
        float as1 = aatt[head1 * 384 + col], ad1 = aatt[head1 * 384 + 128 + col];
#pragma unroll
        for (int r = 0; r < 4; ++r) {
            int row = lg * 4 + r;
            float z0 = acc[0][nt][r] + b0;
            float z1 = acc[1][nt][r] + b1;
            unsigned pk = __builtin_amdgcn_cvt_pk_fp8_f32(z0, z1, 0, false);
            lds[row * 520 + col * 4 + wid] = (unsigned short)(pk & 0xffffu);
            ps[0][r] = fmaf(z0, as0, ps[0][r]);
            pd[0][r] = fmaf(z0, ad0, pd[0][r]);
            ps[1][r] = fmaf(z1, as1, ps[1][r]);
            pd[1][r] = fmaf(z1, ad1, pd[1][r]);
        }
    }
#pragma unroll
    for (int o = 1; o < 16; o <<= 1) {
#pragma unroll
        for (int hh = 0; hh < 2; ++hh)
#pragma unroll
            for (int r = 0; r < 4; ++r) {
                ps[hh][r] += __shfl_xor(ps[hh][r], o, 64);
                pd[hh][r] += __shfl_xor(pd[hh][r], o, 64);
            }
    }
    if (lr == 0) {
#pragma unroll
        for (int hh = 0; hh < 2; ++hh) {
            int head = wid * 2 + hh;
#pragma unroll
            for (int r = 0; r < 4; ++r) {
                int n = n0 + lg * 4 + r;
                s_src[n * 8 + head] = ps[hh][r];
                s_dst[n * 8 + head] = pd[hh][r];
            }
        }
    }
    __syncthreads();
    unsigned short* zt8u = reinterpret_cast<unsigned short*>(zt8);
    for (int q = t; q < 16 * 64; q += 256) {
        int row = q >> 6, c = q & 63;
        *reinterpret_cast<uint4*>(&zt8u[(size_t)(n0 + row) * 512 + c * 8]) =
            *reinterpret_cast<const uint4*>(&lds[row * 520 + c * 8]);
    }
}

// ---------------- P12 (bf16) = node @ [W1|W2], MFMA, out N x 256 ----------------
__global__ void __launch_bounds__(256) k_p12_mfma(
        const unsigned short* __restrict__ node_bf, const unsigned short* __restrict__ WtE,
        unsigned short* __restrict__ p12, int N) {
    __shared__ unsigned short ash[64][136];
    int n0 = blockIdx.x * 64;
    int s = blockIdx.y;
    int t = threadIdx.x;
    for (int q = t; q < 64 * 16; q += 256) {
        int r = q >> 4, c = q & 15;
        int n = n0 + r; if (n >= N) n = N - 1;
        *reinterpret_cast<uint4*>(&ash[r][c * 8]) =
            *reinterpret_cast<const uint4*>(node_bf + (size_t)n * 128 + c * 8);
    }
    __syncthreads();

    int wid = t >> 6, lane = t & 63;
    int wm = wid >> 1, wn = wid & 1;
    int lr = lane & 15, lg = lane >> 4;

    f32x4 acc[2][4];
#pragma unroll
    for (int m = 0; m < 2; ++m)
#pragma unroll
        for (int n = 0; n < 4; ++n) acc[m][n] = (f32x4){0.f, 0.f, 0.f, 0.f};

    const unsigned short* Wh = WtE + (size_t)s * 16384;
#pragma unroll
    for (int ks = 0; ks < 4; ++ks) {
        int kb = ks * 32 + lg * 8;
        bf16x8 a0 = *reinterpret_cast<const bf16x8*>(&ash[wm * 32 + lr][kb]);
        bf16x8 a1 = *reinterpret_cast<const bf16x8*>(&ash[wm * 32 + 16 + lr][kb]);
        bf16x8 b[4];
#pragma unroll
        for (int n = 0; n < 4; ++n)
            b[n] = *reinterpret_cast<const bf16x8*>(Wh + (size_t)(wn * 64 + n * 16 + lr) * 128 + kb);
#pragma unroll
        for (int n = 0; n < 4; ++n) {
            acc[0][n] = __builtin_amdgcn_mfma_f32_16x16x32_bf16(a0, b[n], acc[0][n], 0, 0, 0);
            acc[1][n] = __builtin_amdgcn_mfma_f32_16x16x32_bf16(a1, b[n], acc[1][n], 0, 0, 0);
        }
    }

    __syncthreads();
    unsigned short* ot = &ash[0][0];
#pragma unroll
    for (int n = 0; n < 4; ++n) {
        int col = wn * 64 + n * 16 + lr;
#pragma unroll
        for (int m = 0; m < 2; ++m) {
            int rowb = wm * 32 + m * 16 + lg * 4;
#pragma unroll
            for (int r = 0; r < 4; ++r)
                ot[(rowb + r) * 136 + col] = f2bf(acc[m][n][r]);
        }
    }
    __syncthreads();
    for (int q = t; q < 64 * 16; q += 256) {
        int r = q >> 4, c = q & 15;
        int row = n0 + r;
        if (row < N)
            *reinterpret_cast<uint4*>(&p12[(size_t)row * 256 + s * 128 + c * 8]) =
                *reinterpret_cast<const uint4*>(&ot[r * 136 + c * 8]);
    }
}

// ---------------- PE+combine fused: 64-edge two-buffer; nt-load eattr ----------------
__global__ void __launch_bounds__(256) k_pe_comb(
        const float* __restrict__ eattr, const unsigned short* __restrict__ WtE,
        const float* __restrict__ be, const unsigned short* __restrict__ p12,
        const int* __restrict__ eidx, unsigned short* __restrict__ ebuf,
        float* __restrict__ part) {
    __shared__ unsigned short ash[64][136];     // A-tile, then C-tile
    __shared__ unsigned short pcomb[64][136];   // p1[src]+p2[dst]
    __shared__ int sd[128];
    __shared__ float sbuf[4][64], qbuf[4][64];
    int e0 = blockIdx.x * 64;
    int t = threadIdx.x;
    if (t < 128) sd[t] = eidx[e0 * 2 + t];      // [e][0]=dst, [e][1]=src
    __syncthreads();
    for (int q = t; q < 64 * 32; q += 256) {
        int r = q >> 5, c = q & 31;
        f32x4 v = __builtin_nontemporal_load(
            reinterpret_cast<const f32x4*>(eattr + (size_t)(e0 + r) * 128 + c * 4));
        ushort4 o;
        o.x = f2bf(v.x); o.y = f2bf(v.y); o.z = f2bf(v.z); o.w = f2bf(v.w);
        *reinterpret_cast<ushort4*>(&ash[r][c * 4]) = o;
    }
    for (int q = t; q < 64 * 16; q += 256) {
        int r = q >> 4, c = q & 15;
        int dst = sd[r * 2], src = sd[r * 2 + 1];
        u16x8 a = *reinterpret_cast<const u16x8*>(p12 + (size_t)src * 256 + c * 8);
        u16x8 b = *reinterpret_cast<const u16x8*>(p12 + (size_t)dst * 256 + 128 + c * 8);
        u16x8 o;
#pragma unroll
        for (int j = 0; j < 8; ++j) o[j] = f2bf(bf2f(a[j]) + bf2f(b[j]));
        *reinterpret_cast<u16x8*>(&pcomb[r][c * 8]) = o;
    }
    __syncthreads();

    int wid = t >> 6, lane = t & 63;
    int wm = wid >> 1, wn = wid & 1;
    int lr = lane & 15, lg = lane >> 4;

    f32x4 acc[2][4];
#pragma unroll
    for (int m = 0; m < 2; ++m)
#pragma unroll
        for (int n = 0; n < 4; ++n) acc[m][n] = (f32x4){0.f, 0.f, 0.f, 0.f};

    const unsigned short* Wh = WtE + (size_t)2 * 16384;
#pragma unroll
    for (int ks = 0; ks < 4; ++ks) {
        int kb = ks * 32 + lg * 8;
        bf16x8 a0 = *reinterpret_cast<const bf16x8*>(&ash[wm * 32 + lr][kb]);
        bf16x8 a1 = *reinterpret_cast<const bf16x8*>(&ash[wm * 32 + 16 + lr][kb]);
        bf16x8 b[4];
#pragma unroll
        for (int n = 0; n < 4; ++n)
            b[n] = *reinterpret_cast<const bf16x8*>(Wh + (size_t)(wn * 64 + n * 16 + lr) * 128 + kb);
#pragma unroll
        for (int n = 0; n < 4; ++n) {
            acc[0][n] = __builtin_amdgcn_mfma_f32_16x16x32_bf16(a0, b[n], acc[0][n], 0, 0, 0);
            acc[1][n] = __builtin_amdgcn_mfma_f32_16x16x32_bf16(a1, b[n], acc[1][n], 0, 0, 0);
        }
    }

    __syncthreads();                      // A dead; reuse ash as C-tile
    unsigned short* ot = &ash[0][0];
    float s[4] = {0.f, 0.f, 0.f, 0.f}, q[4] = {0.f, 0.f, 0.f, 0.f};
#pragma unroll
    for (int n = 0; n < 4; ++n) {
        int col = wn * 64 + n * 16 + lr;
        float bias = be[col];
#pragma unroll
        for (int m = 0; m < 2; ++m) {
            int rowb = wm * 32 + m * 16 + lg * 4;
#pragma unroll
            for (int r = 0; r < 4; ++r) {
                int row = rowb + r;
                float v = acc[m][n][r] + bias + bf2f(pcomb[row][col]);
                v = v > 0.f ? v : 0.f;
                ot[row * 136 + col] = f2bf(v);
                s[n] += v;
                q[n] += v * v;
            }
        }
    }
#pragma unroll
    for (int n = 0; n < 4; ++n) {
        s[n] += __shfl_xor(s[n], 16, 64);
        s[n] += __shfl_xor(s[n], 32, 64);
        q[n] += __shfl_xor(q[n], 16, 64);
        q[n] += __shfl_xor(q[n], 32, 64);
    }
    if (lane < 16) {
#pragma unroll
        for (int n = 0; n < 4; ++n) {
            sbuf[wid][n * 16 + lane] = s[n];
            qbuf[wid][n * 16 + lane] = q[n];
        }
    }
    __syncthreads();
    for (int q2 = t; q2 < 64 * 16; q2 += 256) {
        int r = q2 >> 4, c = q2 & 15;
        *reinterpret_cast<uint4*>(&ebuf[(size_t)(e0 + r) * 128 + c * 8]) =
            *reinterpret_cast<const uint4*>(&ot[r * 136 + c * 8]);
    }
    if (t < 128) {
        int half = t >> 6, c = t & 63;
        part[(size_t)blockIdx.x * 256 + t] = sbuf[half][c] + sbuf[2 + half][c];
        part[(size_t)blockIdx.x * 256 + 128 + t] = qbuf[half][c] + qbuf[2 + half][c];
    }
}

// ---------------- node MLP via MFMA: relu(node @ W_node + b) -> bf16, BN partials ----------------
__global__ void __launch_bounds__(256) k_node_mlp_mfma(
        const unsigned short* __restrict__ node_bf, const unsigned short* __restrict__ WnT,
        const float* __restrict__ bn, unsigned short* __restrict__ nupd_bf,
        float* __restrict__ part, int N) {
    __shared__ unsigned short ash[64][136];
    __shared__ float sbuf[4][64], qbuf[4][64];
    int n0 = blockIdx.x * 64;
    int t = threadIdx.x;
    for (int q = t; q < 64 * 16; q += 256) {
        int r = q >> 4, c = q & 15;
        int n = n0 + r; if (n >= N) n = N - 1;
        *reinterpret_cast<uint4*>(&ash[r][c * 8]) =
            *reinterpret_cast<const uint4*>(node_bf + (size_t)n * 128 + c * 8);
    }
    __syncthreads();

    int wid = t >> 6, lane = t & 63;
    int wm = wid >> 1, wn = wid & 1;
    int lr = lane & 15, lg = lane >> 4;

    f32x4 acc[2][4];
#pragma unroll
    for (int m = 0; m < 2; ++m)
#pragma unroll
        for (int n = 0; n < 4; ++n) acc[m][n] = (f32x4){0.f, 0.f, 0.f, 0.f};

#pragma unroll
    for (int ks = 0; ks < 4; ++ks) {
        int kb = ks * 32 + lg * 8;
        bf16x8 a0 = *reinterpret_cast<const bf16x8*>(&ash[wm * 32 + lr][kb]);
        bf16x8 a1 = *reinterpret_cast<const bf16x8*>(&ash[wm * 32 + 16 + lr][kb]);
        bf16x8 b[4];
#pragma unroll
        for (int n = 0; n < 4; ++n)
            b[n] = *reinterpret_cast<const bf16x8*>(WnT + (size_t)(wn * 64 + n * 16 + lr) * 128 + kb);
#pragma unroll
        for (int n = 0; n < 4; ++n) {
            acc[0][n] = __builtin_amdgcn_mfma_f32_16x16x32_bf16(a0, b[n], acc[0][n], 0, 0, 0);
            acc[1][n] = __builtin_amdgcn_mfma_f32_16x16x32_bf16(a1, b[n], acc[1][n], 0, 0, 0);
        }
    }

    __syncthreads();
    unsigned short* ot = &ash[0][0];
    float s[4] = {0.f, 0.f, 0.f, 0.f}, q[4] = {0.f, 0.f, 0.f, 0.f};
#pragma unroll
    for (int n = 0; n < 4; ++n) {
        int col = wn * 64 + n * 16 + lr;
        float bias = bn[col];
#pragma unroll
        for (int m = 0; m < 2; ++m) {
            int rowb = wm * 32 + m * 16 + lg * 4;
#pragma unroll
            for (int r = 0; r < 4; ++r) {
                int row = n0 + rowb + r;
                float v = acc[m][n][r] + bias;
                v = v > 0.f ? v : 0.f;
                ot[(rowb + r) * 136 + col] = f2bf(v);
                if (row < N) { s[n] += v; q[n] += v * v; }
            }
        }
    }
#pragma unroll
    for (int n = 0; n < 4; ++n) {
        s[n] += __shfl_xor(s[n], 16, 64);
        s[n] += __shfl_xor(s[n], 32, 64);
        q[n] += __shfl_xor(q[n], 16, 64);
        q[n] += __shfl_xor(q[n], 32, 64);
    }
    if (lane < 16) {
#pragma unroll
        for (int n = 0; n < 4; ++n) {
            sbuf[wid][n * 16 + lane] = s[n];
            qbuf[wid][n * 16 + lane] = q[n];
        }
    }
    __syncthreads();
    for (int q2 = t; q2 < 64 * 16; q2 += 256) {
        int r = q2 >> 4, c = q2 & 15;
        int row = n0 + r;
        if (row < N)
            *reinterpret_cast<uint4*>(&nupd_bf[(size_t)row * 128 + c * 8]) =
                *reinterpret_cast<const uint4*>(&ot[r * 136 + c * 8]);
    }
    if (t < 128) {
        int half = t >> 6, c = t & 63;
        part[(size_t)blockIdx.x * 256 + t] = sbuf[half][c] + sbuf[2 + half][c];
        part[(size_t)blockIdx.x * 256 + 128 + t] = qbuf[half][c] + qbuf[2 + half][c];
    }
}

// ---------------- BN finalize (combined edge+node): 256 blocks ----------------
__global__ void k_bn_fin2(const float* __restrict__ part_e, int nblk_e, float invcnt_e,
                          const float* __restrict__ g_e, const float* __restrict__ b_e,
                          float* __restrict__ scale_e, float* __restrict__ shift_e,
                          const float* __restrict__ part_n, int nblk_n, float invcnt_n,
                          const float* __restrict__ g_n, const float* __restrict__ b_n,
                          float* __restrict__ scale_n, float* __restrict__ shift_n) {
    bool is_edge = blockIdx.x < 128;
    int u = is_edge ? blockIdx.x : blockIdx.x - 128;
    const float* part = is_edge ? part_e : part_n;
    int nblk = is_edge ? nblk_e : nblk_n;
    float invcnt = is_edge ? invcnt_e : invcnt_n;
    const float* g = is_edge ? g_e : g_n;
    const float* b = is_edge ? b_e : b_n;
    float* scale = is_edge ? scale_e : scale_n;
    float* shift = is_edge ? shift_e : shift_n;

    int t = threadIdx.x;
    float s = 0.f, q = 0.f;
    for (int i = t; i < nblk; i += 256) {
        s += part[(size_t)i * 256 + u];
        q += part[(size_t)i * 256 + 128 + u];
    }
    __shared__ float ls[4], lq[4];
    for (int o = 32; o > 0; o >>= 1) {
        s += __shfl_down(s, o, 64);
        q += __shfl_down(q, o, 64);
    }
    int lane = t & 63, w = t >> 6;
    if (lane == 0) { ls[w] = s; lq[w] = q; }
    __syncthreads();
    if (t == 0) {
        float S = ls[0] + ls[1] + ls[2] + ls[3];
        float Q = lq[0] + lq[1] + lq[2] + lq[3];
        float mean = S * invcnt;
        float var = Q * invcnt - mean * mean;
        float inv = rsqrtf(var + BN_EPS);
        float sc = g[u] * inv;
        scale[u] = sc;
        shift[u] = b[u] - mean * sc;
    }
}

// ---------------- edge finalize + fused lsum: BN apply, eout, ls[pos[e]] ----------------
__global__ void __launch_bounds__(256) k_edge_final(
        const unsigned short* __restrict__ ebuf, const float* __restrict__ scale,
        const float* __restrict__ shift, const float* __restrict__ aatt,
        const int* __restrict__ eidx, const int* __restrict__ pos,
        const float* __restrict__ s_src,
        float* __restrict__ eout, float* __restrict__ ls, int* __restrict__ srcl) {
    int t = threadIdx.x;
    int w = t >> 6, lane = t & 63;
    int q = lane & 31, half = lane >> 5;
    int e = blockIdx.x * 8 + w * 2 + half;

    float4 sc = *reinterpret_cast<const float4*>(scale + q * 4);
    float4 sh = *reinterpret_cast<const float4*>(shift + q * 4);
    float4 a4[8];
#pragma unroll
    for (int h = 0; h < 8; ++h)
        a4[h] = *reinterpret_cast<const float4*>(aatt + h * 384 + 256 + q * 4);

    ushort4 xb = *reinterpret_cast<const ushort4*>(ebuf + (size_t)e * 128 + q * 4);
    float4 x;
    x.x = bf2f(xb.x) * sc.x + sh.x;
    x.y = bf2f(xb.y) * sc.y + sh.y;
    x.z = bf2f(xb.z) * sc.z + sh.z;
    x.w = bf2f(xb.w) * sc.w + sh.w;
    *reinterpret_cast<float4*>(eout + (size_t)e * 128 + q * 4) = x;

    float v[8];
#pragma unroll
    for (int h = 0; h < 8; ++h)
        v[h] = x.x * a4[h].x + x.y * a4[h].y + x.z * a4[h].z + x.w * a4[h].w;
#pragma unroll
    for (int o = 1; o < 32; o <<= 1) {
#pragma unroll
        for (int h = 0; h < 8; ++h) v[h] += __shfl_xor(v[h], o, 64);
    }
    if (q == 0) {
        int src = eidx[2 * e + 1];
        int p = pos[e];
        srcl[p] = src;
        float4 a0 = *reinterpret_cast<const float4*>(s_src + (size_t)src * 8);
        float4 a1 = *reinterpret_cast<const float4*>(s_src + (size_t)src * 8 + 4);
        float4 o0, o1;
        o0.x = v[0] + a0.x; o0.y = v[1] + a0.y; o0.z = v[2] + a0.z; o0.w = v[3] + a0.w;
        o1.x = v[4] + a1.x; o1.y = v[5] + a1.y; o1.z = v[6] + a1.z; o1.w = v[7] + a1.w;
        *reinterpret_cast<float4*>(ls + (size_t)p * 8) = o0;
        *reinterpret_cast<float4*>(ls + (size_t)p * 8 + 4) = o1;
    }
}

// ---------------- attention: wave-per-node, no barriers, no-max softmax, fp8 messages ----------------
__global__ void __launch_bounds__(256) k_agg(
        const unsigned char* __restrict__ zt8, const float* __restrict__ ls,
        const int* __restrict__ srcl, const float* __restrict__ s_dst,
        const int* __restrict__ off, unsigned short* __restrict__ cat) {
    int wv = threadIdx.x >> 6, lane = threadIdx.x & 63;
    int n = blockIdx.x * 4 + wv;           // grid = NN/4 exactly
    __shared__ float wbuf[4][64][8];
    __shared__ int snbuf[4][64];

    int beg = off[n], end = off[n + 1];
    int deg = end - beg;
    if (deg == 0) {
        cat[(size_t)n * 256 + lane] = 0;
        cat[(size_t)n * 256 + 64 + lane] = 0;
        return;
    }

    float sdh[8];
#pragma unroll
    for (int h = 0; h < 8; ++h) sdh[h] = s_dst[n * 8 + h];

    float den[8], a0v[8], a1v[8];
#pragma unroll
    for (int h = 0; h < 8; ++h) { den[h] = 0.f; a0v[h] = 0.f; a1v[h] = 0.f; }

    for (int c0 = 0; c0 < deg; c0 += 64) {
        int cn = min(64, deg - c0);
        if (lane < cn) {
            int p = beg + c0 + lane;
            snbuf[wv][lane] = srcl[p];
            float4 l0 = *reinterpret_cast<const float4*>(ls + (size_t)p * 8);
            float4 l1 = *reinterpret_cast<const float4*>(ls + (size_t)p * 8 + 4);
            float lg[8] = {l0.x, l0.y, l0.z, l0.w, l1.x, l1.y, l1.z, l1.w};
#pragma unroll
            for (int h = 0; h < 8; ++h) {
                float x = lg[h] + sdh[h];
                x = x >= 0.f ? x : 0.2f * x;
                wbuf[wv][lane][h] = __expf(x);     // no max-subtraction (shift-invariant)
            }
        }
        // wave-synchronous: same wave wrote wbuf/snbuf, lockstep => no barrier needed
        for (int i = 0; i < cn; ++i) {
            int sn_i = snbuf[wv][i];
            const unsigned char* zr = zt8 + (size_t)sn_i * 1024 + (size_t)lane * 8;
            uint2 zv0 = *reinterpret_cast<const uint2*>(zr);
            uint2 zv1 = *reinterpret_cast<const uint2*>(zr + 512);
            float4 w0 = *reinterpret_cast<const float4*>(&wbuf[wv][i][0]);
            float4 w1 = *reinterpret_cast<const float4*>(&wbuf[wv][i][4]);
            f32x2 q01 = __builtin_amdgcn_cvt_pk_f32_fp8(zv0.x, false);
            f32x2 q23 = __builtin_amdgcn_cvt_pk_f32_fp8(zv0.x, true);
            f32x2 q45 = __builtin_amdgcn_cvt_pk_f32_fp8(zv0.y, false);
            f32x2 q67 = __builtin_amdgcn_cvt_pk_f32_fp8(zv0.y, true);
            f32x2 r01 = __builtin_amdgcn_cvt_pk_f32_fp8(zv1.x, false);
            f32x2 r23 = __builtin_amdgcn_cvt_pk_f32_fp8(zv1.x, true);
            f32x2 r45 = __builtin_amdgcn_cvt_pk_f32_fp8(zv1.y, false);
            f32x2 r67 = __builtin_amdgcn_cvt_pk_f32_fp8(zv1.y, true);
            den[0] += w0.x; a0v[0] = fmaf(w0.x, q01.x, a0v[0]); a1v[0] = fmaf(w0.x, r01.x, a1v[0]);
            den[1] += w0.y; a0v[1] = fmaf(w0.y, q01.y, a0v[1]); a1v[1] = fmaf(w0.y, r01.y, a1v[1]);
            den[2] += w0.z; a0v[2] = fmaf(w0.z, q23.x, a0v[2]); a1v[2] = fmaf(w0.z, r23.x, a1v[2]);
            den[3] += w0.w; a0v[3] = fmaf(w0.w, q23.y, a0v[3]); a1v[3] = fmaf(w0.w, r23.y, a1v[3]);
            den[4] += w1.x; a0v[4] = fmaf(w1.x, q45.x, a0v[4]); a1v[4] = fmaf(w1.x, r45.x, a1v[4]);
            den[5] += w1.y; a0v[5] = fmaf(w1.y, q45.y, a0v[5]); a1v[5] = fmaf(w1.y, r45.y, a1v[5]);
            den[6] += w1.z; a0v[6] = fmaf(w1.z, q67.x, a0v[6]); a1v[6] = fmaf(w1.z, r67.x, a1v[6]);
            den[7] += w1.w; a0v[7] = fmaf(w1.w, q67.y, a0v[7]); a1v[7] = fmaf(w1.w, r67.y, a1v[7]);
        }
    }
    float r0 = 0.f, r1 = 0.f;
#pragma unroll
    for (int h = 0; h < 8; ++h) {
        float inv = 1.f / den[h];
        r0 = fmaf(a0v[h], inv, r0);
        r1 = fmaf(a1v[h], inv, r1);
    }
    cat[(size_t)n * 256 + lane] = f2bf(fmaxf(r0 * 0.125f, 0.f));
    cat[(size_t)n * 256 + 64 + lane] = f2bf(fmaxf(r1 * 0.125f, 0.f));
}

// ---------------- GRU pre: cat[:,128:256] = bf16(BN(nupd_bf)) ----------------
__global__ void k_gru_pre(const unsigned short* __restrict__ nupd_bf, const float* __restrict__ scale,
                          const float* __restrict__ shift, unsigned short* __restrict__ cat) {
    int i = blockIdx.x * 256 + threadIdx.x;
    if (i >= NN * 32) return;
    int n = i >> 5, j4 = (i & 31) * 4;
    ushort4 ub_in = *reinterpret_cast<const ushort4*>(nupd_bf + (size_t)n * 128 + j4);
    float4 sc = *reinterpret_cast<const float4*>(scale + j4);
    float4 sh = *reinterpret_cast<const float4*>(shift + j4);
    ushort4 ub;
    ub.x = f2bf(bf2f(ub_in.x) * sc.x + sh.x);
    ub.y = f2bf(bf2f(ub_in.y) * sc.y + sh.y);
    ub.z = f2bf(bf2f(ub_in.z) * sc.z + sh.z);
    ub.w = f2bf(bf2f(ub_in.w) * sc.w + sh.w);
    *reinterpret_cast<ushort4*>(cat + (size_t)n * 256 + 128 + j4) = ub;
}

// ---------------- GRU fused: S = cat @ Wc (all 4 col-groups) + gates, out_node ----------------
__global__ void __launch_bounds__(256) k_gru_fused(
        const unsigned short* __restrict__ cat, const unsigned short* __restrict__ WcT,
        const unsigned short* __restrict__ nupd_bf, const float* __restrict__ scale,
        const float* __restrict__ shift, const float* __restrict__ gbias,
        float* __restrict__ outp, int N) {
    __shared__ unsigned short ash[64][264];      // A (bf16); reused as f32 out [64][132]
    int n0 = blockIdx.x * 64;
    int t = threadIdx.x;
    for (int q = t; q < 64 * 32; q += 256) {
        int r = q >> 5, c = q & 31;
        int n = n0 + r; if (n >= N) n = N - 1;
        *reinterpret_cast<uint4*>(&ash[r][c * 8]) =
            *reinterpret_cast<const uint4*>(cat + (size_t)n * 256 + c * 8);
    }
    __syncthreads();

    int wid = t >> 6, lane = t & 63;
    int wm = wid >> 1, wn = wid & 1;
    int lr = lane & 15, lg = lane >> 4;

    f32x4 acc[4][2][4];                          // [group][m][n]
#pragma unroll
    for (int g = 0; g < 4; ++g)
#pragma unroll
        for (int m = 0; m < 2; ++m)
#pragma unroll
            for (int n = 0; n < 4; ++n) acc[g][m][n] = (f32x4){0.f, 0.f, 0.f, 0.f};

#pragma unroll
    for (int ks = 0; ks < 8; ++ks) {
        int kb = ks * 32 + lg * 8;
        bf16x8 a0 = *reinterpret_cast<const bf16x8*>(&ash[wm * 32 + lr][kb]);
        bf16x8 a1 = *reinterpret_cast<const bf16x8*>(&ash[wm * 32 + 16 + lr][kb]);
#pragma unroll
        for (int g = 0; g < 4; ++g) {
            const unsigned short* Wg = WcT + (size_t)g * 128 * 256;
#pragma unroll
            for (int n = 0; n < 4; ++n) {
                bf16x8 b = *reinterpret_cast<const bf16x8*>(Wg + (size_t)(wn * 64 + n * 16 + lr) * 256 + kb);
                acc[g][0][n] = __builtin_amdgcn_mfma_f32_16x16x32_bf16(a0, b, acc[g][0][n], 0, 0, 0);
                acc[g][1][n] = __builtin_amdgcn_mfma_f32_16x16x32_bf16(a1, b, acc[g][1][n], 0, 0, 0);
            }
        }
    }

    __syncthreads();                             // A dead; reuse as f32 out staging
    float* otf = reinterpret_cast<float*>(&ash[0][0]);   // [64][132]
#pragma unroll
    for (int n = 0; n < 4; ++n) {
        int col = wn * 64 + n * 16 + lr;                 // u in 0..127
        float bz  = gbias[col] + gbias[384 + col];
        float br  = gbias[128 + col] + gbias[384 + 128 + col];
        float bxh = gbias[256 + col];
        float brh = gbias[384 + 256 + col];
        float sc = scale[col], sh = shift[col];
#pragma unroll
        for (int m = 0; m < 2; ++m) {
            int rowb = wm * 32 + m * 16 + lg * 4;
#pragma unroll
            for (int r = 0; r < 4; ++r) {
                int row = rowb + r;
                int grow = n0 + row;
                int gr = grow < N ? grow : N - 1;
                float zg = 1.f / (1.f + __expf(-(acc[0][m][n][r] + bz)));
                float rg = 1.f / (1.f + __expf(-(acc[1][m][n][r] + br)));
                float hh = tanhf(acc[2][m][n][r] + bxh + rg * (acc[3][m][n][r] + brh));
                float uv = bf2f(nupd_bf[(size_t)gr * 128 + col]) * sc + sh;
                otf[row * 132 + col] = zg * uv + (1.f - zg) * hh;
            }
        }
    }
    __syncthreads();
    for (int q = t; q < 64 * 32; q += 256) {
        int r = q >> 5, c = q & 31;
        int row = n0 + r;
        if (row < N)
            *reinterpret_cast<float4*>(&outp[(size_t)row * 128 + c * 4]) =
                *reinterpret_cast<const float4*>(&otf[r * 132 + c * 4]);
    }
}

// ---------------- launch ----------------
extern "C" void kernel_launch(void* const* d_in, const int* in_sizes, int n_in,
                              void* d_out, int out_size, void* d_ws, size_t ws_size,
                              hipStream_t stream) {
    const float* node    = (const float*)d_in[0];
    const float* eattr   = (const float*)d_in[1];
    const int*   eidx    = (const int*)d_in[2];
    const float* We      = (const float*)d_in[3];
    const float* be      = (const float*)d_in[4];
    const float* gamma_e = (const float*)d_in[5];
    const float* beta_e  = (const float*)d_in[6];
    const float* Wn      = (const float*)d_in[7];
    const float* bnb     = (const float*)d_in[8];
    const float* gamma_n = (const float*)d_in[9];
    const float* beta_n  = (const float*)d_in[10];
    const float* Watt    = (const float*)d_in[11];
    const float* batt    = (const float*)d_in[12];
    const float* aatt    = (const float*)d_in[13];
    const float* Wk      = (const float*)d_in[14];
    const float* Wr      = (const float*)d_in[15];
    const float* gbias   = (const float*)d_in[16];

    float* out_node = (float*)d_out;
    float* out_edge = out_node + (size_t)NN * UU;

    char* wp = (char*)d_ws;
    auto alloc = [&](size_t bytes) {
        void* p = (void*)wp;
        wp += (bytes + 255) / 256 * 256;
        return p;
    };
    unsigned char* zt8   = (unsigned char*)alloc((size_t)NN * 1024);       // z fp8 in (N,U,H)
    unsigned short* ebuf = (unsigned short*)alloc((size_t)EE * 128 * 2);
    float* s_src   = (float*)alloc((size_t)NN * 8 * 4);
    float* s_dst   = (float*)alloc((size_t)NN * 8 * 4);
    float* lsbuf   = (float*)alloc((size_t)EE * 8 * 4);
    int*   srcl    = (int*)alloc((size_t)EE * 4);
    float* part_e  = (float*)alloc((size_t)2500 * 256 * 4);
    float* part_n  = (float*)alloc((size_t)157 * 256 * 4);
    float* scale_e = (float*)alloc(512);
    float* shift_e = (float*)alloc(512);
    float* scale_n = (float*)alloc(512);
    float* shift_n = (float*)alloc(512);
    unsigned short* nupd_bf = (unsigned short*)alloc((size_t)NN * 128 * 2);
    int*   cnt     = (int*)alloc((size_t)NN * 4);
    int*   offs    = (int*)alloc((size_t)(NN + 1) * 4);
    int*   cursor  = (int*)alloc((size_t)NN * 4);
    int*   elist   = (int*)alloc((size_t)EE * 4);
    int*   pos     = (int*)alloc((size_t)EE * 4);
    unsigned short* node_bf = (unsigned short*)alloc((size_t)NN * 128 * 2);
    unsigned short* WtE     = (unsigned short*)alloc((size_t)3 * 128 * 128 * 2);
    unsigned short* WtA     = (unsigned short*)alloc((size_t)8 * 128 * 128 * 2);
    unsigned short* WnT     = (unsigned short*)alloc((size_t)128 * 128 * 2);
    unsigned short* WcT     = (unsigned short*)alloc((size_t)512 * 256 * 2);
    unsigned short* cat     = (unsigned short*)alloc((size_t)NN * 256 * 2);
    unsigned short* p12     = (unsigned short*)alloc((size_t)NN * 256 * 2);

    hipMemsetAsync(cnt, 0, (size_t)NN * 4, stream);
    k_hist<<<(EE + 255) / 256, 256, 0, stream>>>(eidx, cnt, EE);
    k_scan<<<1, 1024, 0, stream>>>(cnt, offs, cursor, NN);
    k_scatter<<<(EE + 255) / 256, 256, 0, stream>>>(eidx, cursor, elist, pos, EE);

    k_prep<<<2530, 256, 0, stream>>>(node, node_bf, We, WtE, Wn, WnT, Watt, WtA, Wk, Wr, WcT);

    // node-side producers first (s_src needed by fused edge_final)
    k_z8<<<NN / 16, 256, 0, stream>>>(node_bf, WtA, batt, aatt, zt8, s_src, s_dst);
    k_node_mlp_mfma<<<(NN + 63) / 64, 256, 0, stream>>>(node_bf, WnT, bnb, nupd_bf, part_n, NN);

    // edge pipeline
    k_p12_mfma<<<dim3((NN + 63) / 64, 2), 256, 0, stream>>>(node_bf, WtE, p12, NN);
    k_pe_comb<<<EE / 64, 256, 0, stream>>>(eattr, WtE, be, p12, eidx, ebuf, part_e);
    k_bn_fin2<<<256, 256, 0, stream>>>(part_e, EE / 64, 1.f / (float)EE, gamma_e, beta_e, scale_e, shift_e,
                                       part_n, (NN + 63) / 64, 1.f / (float)NN, gamma_n, beta_n, scale_n, shift_n);
    k_edge_final<<<EE / 8, 256, 0, stream>>>(ebuf, scale_e, shift_e, aatt, eidx, pos, s_src,
                                             out_edge, lsbuf, srcl);

    // attention + GRU (fused tail)
    k_agg<<<NN / 4, 256, 0, stream>>>(zt8, lsbuf, srcl, s_dst, offs, cat);
    k_gru_pre<<<(NN * 32 + 255) / 256, 256, 0, stream>>>(nupd_bf, scale_n, shift_n, cat);
    k_gru_fused<<<(NN + 63) / 64, 256, 0, stream>>>(cat, WcT, nupd_bf, scale_n, shift_n,
                                                    gbias, out_node, NN);
}

// Round 22
// 240.082 us; speedup vs baseline: 1.0691x; 1.0691x over previous
//
#include <hip/hip_runtime.h>
#include <hip/hip_bf16.h>

#define NN 10000
#define EE 160000
#define FF 128
#define UU 128
#define HH 8
#define BN_EPS 1e-3f

typedef __attribute__((ext_vector_type(8))) short bf16x8;
typedef __attribute__((ext_vector_type(8))) unsigned short u16x8;
typedef __attribute__((ext_vector_type(4))) unsigned short u16x4;
typedef __attribute__((ext_vector_type(4))) unsigned int u32x4;
typedef __attribute__((ext_vector_type(4))) float f32x4;
typedef __attribute__((ext_vector_type(2))) float f32x2;

static __device__ __forceinline__ unsigned short f2bf(float f) {
    unsigned u = __float_as_uint(f);
    u += 0x7fffu + ((u >> 16) & 1u);
    return (unsigned short)(u >> 16);
}
static __device__ __forceinline__ float bf2f(unsigned short b) {
    return __uint_as_float((unsigned)b << 16);
}

// ---------------- fused prep: node f2bf + all weight transposes (one launch) ----------------
__global__ void k_prep(const float* __restrict__ node, unsigned short* __restrict__ node_bf,
                       const float* __restrict__ We, unsigned short* __restrict__ WtE,
                       const float* __restrict__ Wn, unsigned short* __restrict__ WnT,
                       const float* __restrict__ Watt, unsigned short* __restrict__ WtA,
                       const float* __restrict__ Wk, const float* __restrict__ Wr,
                       unsigned short* __restrict__ WcT) {
    int b = blockIdx.x, t = threadIdx.x;
    if (b < 1250) {
        int i = b * 256 + t;
        float4 v = reinterpret_cast<const float4*>(node)[i];
        ushort4 o;
        o.x = f2bf(v.x); o.y = f2bf(v.y); o.z = f2bf(v.z); o.w = f2bf(v.w);
        reinterpret_cast<ushort4*>(node_bf)[i] = o;
    } else if (b < 1442) {
        int i = (b - 1250) * 256 + t;                // 3*128*128
        int s = i >> 14, rem = i & 16383, u = rem >> 7, k = rem & 127;
        WtE[i] = f2bf(We[(s * 128 + k) * 128 + u]);
    } else if (b < 1506) {
        int i = (b - 1442) * 256 + t;                // 128*128
        int k = i >> 7, u = i & 127;
        WnT[u * 128 + k] = f2bf(Wn[i]);
    } else if (b < 2018) {
        int i = (b - 1506) * 256 + t;                // 8*128*128
        int h = i >> 14, rem = i & 16383, f = rem >> 7, u = rem & 127;
        WtA[h * 16384 + u * 128 + f] = f2bf(Watt[i]);
    } else {
        int i = (b - 2018) * 256 + t;                // 512*256
        int c = i >> 8, k = i & 255;
        float v;
        if (c < 256)       v = (k < 128) ? Wk[k * 384 + c] : Wr[(k - 128) * 384 + c];
        else if (c < 384)  v = (k < 128) ? Wk[k * 384 + c] : 0.f;
        else               v = (k < 128) ? 0.f : Wr[(k - 128) * 384 + (c - 128)];
        WcT[c * 256 + k] = f2bf(v);
    }
}

// ---------------- CSR construction ----------------
__global__ void k_hist(const int* __restrict__ eidx, int* __restrict__ cnt, int E) {
    int e = blockIdx.x * 256 + threadIdx.x;
    if (e < E) atomicAdd(&cnt[eidx[2 * e]], 1);   // dst = eidx[e][0]
}

__global__ void k_scan(const int* __restrict__ cnt, int* __restrict__ off,
                       int* __restrict__ cursor, int N) {
    __shared__ int wpre[16];
    __shared__ int runsh;
    int t = threadIdx.x, lane = t & 63, wv = t >> 6;
    if (t == 0) { off[0] = 0; runsh = 0; }
    __syncthreads();
    for (int base = 0; base < N; base += 1024) {
        int x = (base + t < N) ? cnt[base + t] : 0;
        int s = x;
#pragma unroll
        for (int o = 1; o < 64; o <<= 1) {
            int v = __shfl_up(s, o, 64);
            if (lane >= o) s += v;
        }
        if (lane == 63) wpre[wv] = s;
        __syncthreads();
        if (t == 0) {
            int acc = runsh;
#pragma unroll
            for (int i = 0; i < 16; ++i) { int tmp = wpre[i]; wpre[i] = acc; acc += tmp; }
            runsh = acc;
        }
        __syncthreads();
        int inc = s + wpre[wv];
        if (base + t < N) {
            off[base + t + 1] = inc;
            cursor[base + t] = inc - x;
        }
        __syncthreads();
    }
}

// scatter: elist[p]=e and inverse map pos[e]=p
__global__ void k_scatter(const int* __restrict__ eidx, int* __restrict__ cursor,
                          int* __restrict__ elist, int* __restrict__ pos, int E) {
    int e = blockIdx.x * 256 + threadIdx.x;
    if (e < E) {
        int d = eidx[2 * e];
        int p = atomicAdd(&cursor[d], 1);
        elist[p] = e;
        pos[e] = p;
    }
}

// ---------------- z (fp8 e4m3, (N,U,H)) = node @ W_att + b_att; fused s_src/s_dst ----------------
__global__ void __launch_bounds__(256) k_z8(
        const unsigned short* __restrict__ node_bf, const unsigned short* __restrict__ WtA,
        const float* __restrict__ batt, const float* __restrict__ aatt,
        unsigned char* __restrict__ zt8, float* __restrict__ s_src, float* __restrict__ s_dst) {
    __shared__ unsigned short lds[16 * 1032];
    int n0 = blockIdx.x * 16;
    int t = threadIdx.x;
    {
        int r = t >> 4, c = t & 15;
        *reinterpret_cast<uint4*>(&lds[r * 136 + c * 8]) =
            *reinterpret_cast<const uint4*>(node_bf + (size_t)(n0 + r) * 128 + c * 8);
    }
    __syncthreads();

    int wid = t >> 6, lane = t & 63;
    int lr = lane & 15, lg = lane >> 4;

    f32x4 acc[2][8];
#pragma unroll
    for (int hh = 0; hh < 2; ++hh)
#pragma unroll
        for (int nt = 0; nt < 8; ++nt) acc[hh][nt] = (f32x4){0.f, 0.f, 0.f, 0.f};

#pragma unroll
    for (int ks = 0; ks < 4; ++ks) {
        int kb = ks * 32 + lg * 8;
        bf16x8 a = *reinterpret_cast<const bf16x8*>(&lds[lr * 136 + kb]);
#pragma unroll
        for (int hh = 0; hh < 2; ++hh) {
            const unsigned short* Wh = WtA + (size_t)(wid * 2 + hh) * 16384;
#pragma unroll
            for (int nt = 0; nt < 8; ++nt) {
                bf16x8 b = *reinterpret_cast<const bf16x8*>(Wh + (size_t)(nt * 16 + lr) * 128 + kb);
                acc[hh][nt] = __builtin_amdgcn_mfma_f32_16x16x32_bf16(a, b, acc[hh][nt], 0, 0, 0);
            }
        }
    }

    __syncthreads();                      // A reads done; reuse lds as fp8 C, row stride 520 u16
    int head0 = wid * 2, head1 = wid * 2 + 1;
    float ps[2][4], pd[2][4];
#pragma unroll
    for (int hh = 0; hh < 2; ++hh)
#pragma unroll
        for (int r = 0; r < 4; ++r) { ps[hh][r] = 0.f; pd[hh][r] = 0.f; }

#pragma unroll
    for (int nt = 0; nt < 8; ++nt) {
        int col = nt * 16 + lr;
        float b0 = batt[head0 * 128 + col], b1 = batt[head1 * 128 + col];
        float as0 = aatt[head0 * 384 + col], ad0 = aatt[head0 * 384 + 128 + col];
        float as1 = aatt[head1 * 384 + col], ad1 = aatt[head1 * 384 + 128 + col];
#pragma unroll
        for (int r = 0; r < 4; ++r) {
            int row = lg * 4 + r;
            float z0 = acc[0][nt][r] + b0;
            float z1 = acc[1][nt][r] + b1;
            unsigned pk = __builtin_amdgcn_cvt_pk_fp8_f32(z0, z1, 0, false);
            lds[row * 520 + col * 4 + wid] = (unsigned short)(pk & 0xffffu);
            ps[0][r] = fmaf(z0, as0, ps[0][r]);
            pd[0][r] = fmaf(z0, ad0, pd[0][r]);
            ps[1][r] = fmaf(z1, as1, ps[1][r]);
            pd[1][r] = fmaf(z1, ad1, pd[1][r]);
        }
    }
#pragma unroll
    for (int o = 1; o < 16; o <<= 1) {
#pragma unroll
        for (int hh = 0; hh < 2; ++hh)
#pragma unroll
            for (int r = 0; r < 4; ++r) {
                ps[hh][r] += __shfl_xor(ps[hh][r], o, 64);
                pd[hh][r] += __shfl_xor(pd[hh][r], o, 64);
            }
    }
    if (lr == 0) {
#pragma unroll
        for (int hh = 0; hh < 2; ++hh) {
            int head = wid * 2 + hh;
#pragma unroll
            for (int r = 0; r < 4; ++r) {
                int n = n0 + lg * 4 + r;
                s_src[n * 8 + head] = ps[hh][r];
                s_dst[n * 8 + head] = pd[hh][r];
            }
        }
    }
    __syncthreads();
    unsigned short* zt8u = reinterpret_cast<unsigned short*>(zt8);
    for (int q = t; q < 16 * 64; q += 256) {
        int row = q >> 6, c = q & 63;
        *reinterpret_cast<uint4*>(&zt8u[(size_t)(n0 + row) * 512 + c * 8]) =
            *reinterpret_cast<const uint4*>(&lds[row * 520 + c * 8]);
    }
}

// ---------------- P12 (bf16) = node @ [W1|W2], MFMA, out N x 256 ----------------
__global__ void __launch_bounds__(256) k_p12_mfma(
        const unsigned short* __restrict__ node_bf, const unsigned short* __restrict__ WtE,
        unsigned short* __restrict__ p12, int N) {
    __shared__ unsigned short ash[64][136];
    int n0 = blockIdx.x * 64;
    int s = blockIdx.y;
    int t = threadIdx.x;
    for (int q = t; q < 64 * 16; q += 256) {
        int r = q >> 4, c = q & 15;
        int n = n0 + r; if (n >= N) n = N - 1;
        *reinterpret_cast<uint4*>(&ash[r][c * 8]) =
            *reinterpret_cast<const uint4*>(node_bf + (size_t)n * 128 + c * 8);
    }
    __syncthreads();

    int wid = t >> 6, lane = t & 63;
    int wm = wid >> 1, wn = wid & 1;
    int lr = lane & 15, lg = lane >> 4;

    f32x4 acc[2][4];
#pragma unroll
    for (int m = 0; m < 2; ++m)
#pragma unroll
        for (int n = 0; n < 4; ++n) acc[m][n] = (f32x4){0.f, 0.f, 0.f, 0.f};

    const unsigned short* Wh = WtE + (size_t)s * 16384;
#pragma unroll
    for (int ks = 0; ks < 4; ++ks) {
        int kb = ks * 32 + lg * 8;
        bf16x8 a0 = *reinterpret_cast<const bf16x8*>(&ash[wm * 32 + lr][kb]);
        bf16x8 a1 = *reinterpret_cast<const bf16x8*>(&ash[wm * 32 + 16 + lr][kb]);
        bf16x8 b[4];
#pragma unroll
        for (int n = 0; n < 4; ++n)
            b[n] = *reinterpret_cast<const bf16x8*>(Wh + (size_t)(wn * 64 + n * 16 + lr) * 128 + kb);
#pragma unroll
        for (int n = 0; n < 4; ++n) {
            acc[0][n] = __builtin_amdgcn_mfma_f32_16x16x32_bf16(a0, b[n], acc[0][n], 0, 0, 0);
            acc[1][n] = __builtin_amdgcn_mfma_f32_16x16x32_bf16(a1, b[n], acc[1][n], 0, 0, 0);
        }
    }

    __syncthreads();
    unsigned short* ot = &ash[0][0];
#pragma unroll
    for (int n = 0; n < 4; ++n) {
        int col = wn * 64 + n * 16 + lr;
#pragma unroll
        for (int m = 0; m < 2; ++m) {
            int rowb = wm * 32 + m * 16 + lg * 4;
#pragma unroll
            for (int r = 0; r < 4; ++r)
                ot[(rowb + r) * 136 + col] = f2bf(acc[m][n][r]);
        }
    }
    __syncthreads();
    for (int q = t; q < 64 * 16; q += 256) {
        int r = q >> 4, c = q & 15;
        int row = n0 + r;
        if (row < N)
            *reinterpret_cast<uint4*>(&p12[(size_t)row * 256 + s * 128 + c * 8]) =
                *reinterpret_cast<const uint4*>(&ot[r * 136 + c * 8]);
    }
}

// ---------------- PE+combine fused: 64-edge two-buffer; nt-load eattr ----------------
__global__ void __launch_bounds__(256) k_pe_comb(
        const float* __restrict__ eattr, const unsigned short* __restrict__ WtE,
        const float* __restrict__ be, const unsigned short* __restrict__ p12,
        const int* __restrict__ eidx, unsigned short* __restrict__ ebuf,
        float* __restrict__ part) {
    __shared__ unsigned short ash[64][136];     // A-tile, then C-tile
    __shared__ unsigned short pcomb[64][136];   // p1[src]+p2[dst]
    __shared__ int sd[128];
    __shared__ float sbuf[4][64], qbuf[4][64];
    int e0 = blockIdx.x * 64;
    int t = threadIdx.x;
    if (t < 128) sd[t] = eidx[e0 * 2 + t];      // [e][0]=dst, [e][1]=src
    __syncthreads();
    for (int q = t; q < 64 * 32; q += 256) {
        int r = q >> 5, c = q & 31;
        f32x4 v = __builtin_nontemporal_load(
            reinterpret_cast<const f32x4*>(eattr + (size_t)(e0 + r) * 128 + c * 4));
        ushort4 o;
        o.x = f2bf(v.x); o.y = f2bf(v.y); o.z = f2bf(v.z); o.w = f2bf(v.w);
        *reinterpret_cast<ushort4*>(&ash[r][c * 4]) = o;
    }
    for (int q = t; q < 64 * 16; q += 256) {
        int r = q >> 4, c = q & 15;
        int dst = sd[r * 2], src = sd[r * 2 + 1];
        u16x8 a = *reinterpret_cast<const u16x8*>(p12 + (size_t)src * 256 + c * 8);
        u16x8 b = *reinterpret_cast<const u16x8*>(p12 + (size_t)dst * 256 + 128 + c * 8);
        u16x8 o;
#pragma unroll
        for (int j = 0; j < 8; ++j) o[j] = f2bf(bf2f(a[j]) + bf2f(b[j]));
        *reinterpret_cast<u16x8*>(&pcomb[r][c * 8]) = o;
    }
    __syncthreads();

    int wid = t >> 6, lane = t & 63;
    int wm = wid >> 1, wn = wid & 1;
    int lr = lane & 15, lg = lane >> 4;

    f32x4 acc[2][4];
#pragma unroll
    for (int m = 0; m < 2; ++m)
#pragma unroll
        for (int n = 0; n < 4; ++n) acc[m][n] = (f32x4){0.f, 0.f, 0.f, 0.f};

    const unsigned short* Wh = WtE + (size_t)2 * 16384;
#pragma unroll
    for (int ks = 0; ks < 4; ++ks) {
        int kb = ks * 32 + lg * 8;
        bf16x8 a0 = *reinterpret_cast<const bf16x8*>(&ash[wm * 32 + lr][kb]);
        bf16x8 a1 = *reinterpret_cast<const bf16x8*>(&ash[wm * 32 + 16 + lr][kb]);
        bf16x8 b[4];
#pragma unroll
        for (int n = 0; n < 4; ++n)
            b[n] = *reinterpret_cast<const bf16x8*>(Wh + (size_t)(wn * 64 + n * 16 + lr) * 128 + kb);
#pragma unroll
        for (int n = 0; n < 4; ++n) {
            acc[0][n] = __builtin_amdgcn_mfma_f32_16x16x32_bf16(a0, b[n], acc[0][n], 0, 0, 0);
            acc[1][n] = __builtin_amdgcn_mfma_f32_16x16x32_bf16(a1, b[n], acc[1][n], 0, 0, 0);
        }
    }

    __syncthreads();                      // A dead; reuse ash as C-tile
    unsigned short* ot = &ash[0][0];
    float s[4] = {0.f, 0.f, 0.f, 0.f}, q[4] = {0.f, 0.f, 0.f, 0.f};
#pragma unroll
    for (int n = 0; n < 4; ++n) {
        int col = wn * 64 + n * 16 + lr;
        float bias = be[col];
#pragma unroll
        for (int m = 0; m < 2; ++m) {
            int rowb = wm * 32 + m * 16 + lg * 4;
#pragma unroll
            for (int r = 0; r < 4; ++r) {
                int row = rowb + r;
                float v = acc[m][n][r] + bias + bf2f(pcomb[row][col]);
                v = v > 0.f ? v : 0.f;
                ot[row * 136 + col] = f2bf(v);
                s[n] += v;
                q[n] += v * v;
            }
        }
    }
#pragma unroll
    for (int n = 0; n < 4; ++n) {
        s[n] += __shfl_xor(s[n], 16, 64);
        s[n] += __shfl_xor(s[n], 32, 64);
        q[n] += __shfl_xor(q[n], 16, 64);
        q[n] += __shfl_xor(q[n], 32, 64);
    }
    if (lane < 16) {
#pragma unroll
        for (int n = 0; n < 4; ++n) {
            sbuf[wid][n * 16 + lane] = s[n];
            qbuf[wid][n * 16 + lane] = q[n];
        }
    }
    __syncthreads();
    for (int q2 = t; q2 < 64 * 16; q2 += 256) {
        int r = q2 >> 4, c = q2 & 15;
        *reinterpret_cast<uint4*>(&ebuf[(size_t)(e0 + r) * 128 + c * 8]) =
            *reinterpret_cast<const uint4*>(&ot[r * 136 + c * 8]);
    }
    if (t < 128) {
        int half = t >> 6, c = t & 63;
        part[(size_t)blockIdx.x * 256 + t] = sbuf[half][c] + sbuf[2 + half][c];
        part[(size_t)blockIdx.x * 256 + 128 + t] = qbuf[half][c] + qbuf[2 + half][c];
    }
}

// ---------------- node MLP via MFMA: relu(node @ W_node + b) -> bf16, BN partials ----------------
__global__ void __launch_bounds__(256) k_node_mlp_mfma(
        const unsigned short* __restrict__ node_bf, const unsigned short* __restrict__ WnT,
        const float* __restrict__ bn, unsigned short* __restrict__ nupd_bf,
        float* __restrict__ part, int N) {
    __shared__ unsigned short ash[64][136];
    __shared__ float sbuf[4][64], qbuf[4][64];
    int n0 = blockIdx.x * 64;
    int t = threadIdx.x;
    for (int q = t; q < 64 * 16; q += 256) {
        int r = q >> 4, c = q & 15;
        int n = n0 + r; if (n >= N) n = N - 1;
        *reinterpret_cast<uint4*>(&ash[r][c * 8]) =
            *reinterpret_cast<const uint4*>(node_bf + (size_t)n * 128 + c * 8);
    }
    __syncthreads();

    int wid = t >> 6, lane = t & 63;
    int wm = wid >> 1, wn = wid & 1;
    int lr = lane & 15, lg = lane >> 4;

    f32x4 acc[2][4];
#pragma unroll
    for (int m = 0; m < 2; ++m)
#pragma unroll
        for (int n = 0; n < 4; ++n) acc[m][n] = (f32x4){0.f, 0.f, 0.f, 0.f};

#pragma unroll
    for (int ks = 0; ks < 4; ++ks) {
        int kb = ks * 32 + lg * 8;
        bf16x8 a0 = *reinterpret_cast<const bf16x8*>(&ash[wm * 32 + lr][kb]);
        bf16x8 a1 = *reinterpret_cast<const bf16x8*>(&ash[wm * 32 + 16 + lr][kb]);
        bf16x8 b[4];
#pragma unroll
        for (int n = 0; n < 4; ++n)
            b[n] = *reinterpret_cast<const bf16x8*>(WnT + (size_t)(wn * 64 + n * 16 + lr) * 128 + kb);
#pragma unroll
        for (int n = 0; n < 4; ++n) {
            acc[0][n] = __builtin_amdgcn_mfma_f32_16x16x32_bf16(a0, b[n], acc[0][n], 0, 0, 0);
            acc[1][n] = __builtin_amdgcn_mfma_f32_16x16x32_bf16(a1, b[n], acc[1][n], 0, 0, 0);
        }
    }

    __syncthreads();
    unsigned short* ot = &ash[0][0];
    float s[4] = {0.f, 0.f, 0.f, 0.f}, q[4] = {0.f, 0.f, 0.f, 0.f};
#pragma unroll
    for (int n = 0; n < 4; ++n) {
        int col = wn * 64 + n * 16 + lr;
        float bias = bn[col];
#pragma unroll
        for (int m = 0; m < 2; ++m) {
            int rowb = wm * 32 + m * 16 + lg * 4;
#pragma unroll
            for (int r = 0; r < 4; ++r) {
                int row = n0 + rowb + r;
                float v = acc[m][n][r] + bias;
                v = v > 0.f ? v : 0.f;
                ot[(rowb + r) * 136 + col] = f2bf(v);
                if (row < N) { s[n] += v; q[n] += v * v; }
            }
        }
    }
#pragma unroll
    for (int n = 0; n < 4; ++n) {
        s[n] += __shfl_xor(s[n], 16, 64);
        s[n] += __shfl_xor(s[n], 32, 64);
        q[n] += __shfl_xor(q[n], 16, 64);
        q[n] += __shfl_xor(q[n], 32, 64);
    }
    if (lane < 16) {
#pragma unroll
        for (int n = 0; n < 4; ++n) {
            sbuf[wid][n * 16 + lane] = s[n];
            qbuf[wid][n * 16 + lane] = q[n];
        }
    }
    __syncthreads();
    for (int q2 = t; q2 < 64 * 16; q2 += 256) {
        int r = q2 >> 4, c = q2 & 15;
        int row = n0 + r;
        if (row < N)
            *reinterpret_cast<uint4*>(&nupd_bf[(size_t)row * 128 + c * 8]) =
                *reinterpret_cast<const uint4*>(&ot[r * 136 + c * 8]);
    }
    if (t < 128) {
        int half = t >> 6, c = t & 63;
        part[(size_t)blockIdx.x * 256 + t] = sbuf[half][c] + sbuf[2 + half][c];
        part[(size_t)blockIdx.x * 256 + 128 + t] = qbuf[half][c] + qbuf[2 + half][c];
    }
}

// ---------------- BN finalize (combined edge+node): 256 blocks ----------------
__global__ void k_bn_fin2(const float* __restrict__ part_e, int nblk_e, float invcnt_e,
                          const float* __restrict__ g_e, const float* __restrict__ b_e,
                          float* __restrict__ scale_e, float* __restrict__ shift_e,
                          const float* __restrict__ part_n, int nblk_n, float invcnt_n,
                          const float* __restrict__ g_n, const float* __restrict__ b_n,
                          float* __restrict__ scale_n, float* __restrict__ shift_n) {
    bool is_edge = blockIdx.x < 128;
    int u = is_edge ? blockIdx.x : blockIdx.x - 128;
    const float* part = is_edge ? part_e : part_n;
    int nblk = is_edge ? nblk_e : nblk_n;
    float invcnt = is_edge ? invcnt_e : invcnt_n;
    const float* g = is_edge ? g_e : g_n;
    const float* b = is_edge ? b_e : b_n;
    float* scale = is_edge ? scale_e : scale_n;
    float* shift = is_edge ? shift_e : shift_n;

    int t = threadIdx.x;
    float s = 0.f, q = 0.f;
    for (int i = t; i < nblk; i += 256) {
        s += part[(size_t)i * 256 + u];
        q += part[(size_t)i * 256 + 128 + u];
    }
    __shared__ float ls[4], lq[4];
    for (int o = 32; o > 0; o >>= 1) {
        s += __shfl_down(s, o, 64);
        q += __shfl_down(q, o, 64);
    }
    int lane = t & 63, w = t >> 6;
    if (lane == 0) { ls[w] = s; lq[w] = q; }
    __syncthreads();
    if (t == 0) {
        float S = ls[0] + ls[1] + ls[2] + ls[3];
        float Q = lq[0] + lq[1] + lq[2] + lq[3];
        float mean = S * invcnt;
        float var = Q * invcnt - mean * mean;
        float inv = rsqrtf(var + BN_EPS);
        float sc = g[u] * inv;
        scale[u] = sc;
        shift[u] = b[u] - mean * sc;
    }
}

// ---------------- edge finalize + fused lsum: BN apply, eout, ls[pos[e]] ----------------
__global__ void __launch_bounds__(256) k_edge_final(
        const unsigned short* __restrict__ ebuf, const float* __restrict__ scale,
        const float* __restrict__ shift, const float* __restrict__ aatt,
        const int* __restrict__ eidx, const int* __restrict__ pos,
        const float* __restrict__ s_src,
        float* __restrict__ eout, float* __restrict__ ls, int* __restrict__ srcl) {
    int t = threadIdx.x;
    int w = t >> 6, lane = t & 63;
    int q = lane & 31, half = lane >> 5;
    int e = blockIdx.x * 8 + w * 2 + half;

    float4 sc = *reinterpret_cast<const float4*>(scale + q * 4);
    float4 sh = *reinterpret_cast<const float4*>(shift + q * 4);
    float4 a4[8];
#pragma unroll
    for (int h = 0; h < 8; ++h)
        a4[h] = *reinterpret_cast<const float4*>(aatt + h * 384 + 256 + q * 4);

    ushort4 xb = *reinterpret_cast<const ushort4*>(ebuf + (size_t)e * 128 + q * 4);
    float4 x;
    x.x = bf2f(xb.x) * sc.x + sh.x;
    x.y = bf2f(xb.y) * sc.y + sh.y;
    x.z = bf2f(xb.z) * sc.z + sh.z;
    x.w = bf2f(xb.w) * sc.w + sh.w;
    *reinterpret_cast<float4*>(eout + (size_t)e * 128 + q * 4) = x;

    float v[8];
#pragma unroll
    for (int h = 0; h < 8; ++h)
        v[h] = x.x * a4[h].x + x.y * a4[h].y + x.z * a4[h].z + x.w * a4[h].w;
#pragma unroll
    for (int o = 1; o < 32; o <<= 1) {
#pragma unroll
        for (int h = 0; h < 8; ++h) v[h] += __shfl_xor(v[h], o, 64);
    }
    if (q == 0) {
        int src = eidx[2 * e + 1];
        int p = pos[e];
        srcl[p] = src;
        float4 a0 = *reinterpret_cast<const float4*>(s_src + (size_t)src * 8);
        float4 a1 = *reinterpret_cast<const float4*>(s_src + (size_t)src * 8 + 4);
        float4 o0, o1;
        o0.x = v[0] + a0.x; o0.y = v[1] + a0.y; o0.z = v[2] + a0.z; o0.w = v[3] + a0.w;
        o1.x = v[4] + a1.x; o1.y = v[5] + a1.y; o1.z = v[6] + a1.z; o1.w = v[7] + a1.w;
        *reinterpret_cast<float4*>(ls + (size_t)p * 8) = o0;
        *reinterpret_cast<float4*>(ls + (size_t)p * 8 + 4) = o1;
    }
}

// ---------------- attention: wave-per-node, no barriers, no-max softmax, fp8 messages ----------------
__global__ void __launch_bounds__(256) k_agg(
        const unsigned char* __restrict__ zt8, const float* __restrict__ ls,
        const int* __restrict__ srcl, const float* __restrict__ s_dst,
        const int* __restrict__ off, unsigned short* __restrict__ cat) {
    int wv = threadIdx.x >> 6, lane = threadIdx.x & 63;
    int n = blockIdx.x * 4 + wv;           // grid = NN/4 exactly
    __shared__ float wbuf[4][64][8];
    __shared__ int snbuf[4][64];

    int beg = off[n], end = off[n + 1];
    int deg = end - beg;
    if (deg == 0) {
        cat[(size_t)n * 256 + lane] = 0;
        cat[(size_t)n * 256 + 64 + lane] = 0;
        return;
    }

    float sdh[8];
#pragma unroll
    for (int h = 0; h < 8; ++h) sdh[h] = s_dst[n * 8 + h];

    float den[8], a0v[8], a1v[8];
#pragma unroll
    for (int h = 0; h < 8; ++h) { den[h] = 0.f; a0v[h] = 0.f; a1v[h] = 0.f; }

    for (int c0 = 0; c0 < deg; c0 += 64) {
        int cn = min(64, deg - c0);
        if (lane < cn) {
            int p = beg + c0 + lane;
            snbuf[wv][lane] = srcl[p];
            float4 l0 = *reinterpret_cast<const float4*>(ls + (size_t)p * 8);
            float4 l1 = *reinterpret_cast<const float4*>(ls + (size_t)p * 8 + 4);
            float lg[8] = {l0.x, l0.y, l0.z, l0.w, l1.x, l1.y, l1.z, l1.w};
#pragma unroll
            for (int h = 0; h < 8; ++h) {
                float x = lg[h] + sdh[h];
                x = x >= 0.f ? x : 0.2f * x;
                wbuf[wv][lane][h] = __expf(x);     // no max-subtraction (shift-invariant)
            }
        }
        // wave-synchronous: same wave wrote wbuf/snbuf, lockstep => no barrier needed
        for (int i = 0; i < cn; ++i) {
            int sn_i = snbuf[wv][i];
            const unsigned char* zr = zt8 + (size_t)sn_i * 1024 + (size_t)lane * 8;
            uint2 zv0 = *reinterpret_cast<const uint2*>(zr);
            uint2 zv1 = *reinterpret_cast<const uint2*>(zr + 512);
            float4 w0 = *reinterpret_cast<const float4*>(&wbuf[wv][i][0]);
            float4 w1 = *reinterpret_cast<const float4*>(&wbuf[wv][i][4]);
            f32x2 q01 = __builtin_amdgcn_cvt_pk_f32_fp8(zv0.x, false);
            f32x2 q23 = __builtin_amdgcn_cvt_pk_f32_fp8(zv0.x, true);
            f32x2 q45 = __builtin_amdgcn_cvt_pk_f32_fp8(zv0.y, false);
            f32x2 q67 = __builtin_amdgcn_cvt_pk_f32_fp8(zv0.y, true);
            f32x2 r01 = __builtin_amdgcn_cvt_pk_f32_fp8(zv1.x, false);
            f32x2 r23 = __builtin_amdgcn_cvt_pk_f32_fp8(zv1.x, true);
            f32x2 r45 = __builtin_amdgcn_cvt_pk_f32_fp8(zv1.y, false);
            f32x2 r67 = __builtin_amdgcn_cvt_pk_f32_fp8(zv1.y, true);
            den[0] += w0.x; a0v[0] = fmaf(w0.x, q01.x, a0v[0]); a1v[0] = fmaf(w0.x, r01.x, a1v[0]);
            den[1] += w0.y; a0v[1] = fmaf(w0.y, q01.y, a0v[1]); a1v[1] = fmaf(w0.y, r01.y, a1v[1]);
            den[2] += w0.z; a0v[2] = fmaf(w0.z, q23.x, a0v[2]); a1v[2] = fmaf(w0.z, r23.x, a1v[2]);
            den[3] += w0.w; a0v[3] = fmaf(w0.w, q23.y, a0v[3]); a1v[3] = fmaf(w0.w, r23.y, a1v[3]);
            den[4] += w1.x; a0v[4] = fmaf(w1.x, q45.x, a0v[4]); a1v[4] = fmaf(w1.x, r45.x, a1v[4]);
            den[5] += w1.y; a0v[5] = fmaf(w1.y, q45.y, a0v[5]); a1v[5] = fmaf(w1.y, r45.y, a1v[5]);
            den[6] += w1.z; a0v[6] = fmaf(w1.z, q67.x, a0v[6]); a1v[6] = fmaf(w1.z, r67.x, a1v[6]);
            den[7] += w1.w; a0v[7] = fmaf(w1.w, q67.y, a0v[7]); a1v[7] = fmaf(w1.w, r67.y, a1v[7]);
        }
    }
    float r0 = 0.f, r1 = 0.f;
#pragma unroll
    for (int h = 0; h < 8; ++h) {
        float inv = 1.f / den[h];
        r0 = fmaf(a0v[h], inv, r0);
        r1 = fmaf(a1v[h], inv, r1);
    }
    cat[(size_t)n * 256 + lane] = f2bf(fmaxf(r0 * 0.125f, 0.f));
    cat[(size_t)n * 256 + 64 + lane] = f2bf(fmaxf(r1 * 0.125f, 0.f));
}

// ---------------- GRU pre: ush = BN(nupd_bf); cat[:,128:256] = bf16(ush) ----------------
__global__ void k_gru_pre(const unsigned short* __restrict__ nupd_bf, const float* __restrict__ scale,
                          const float* __restrict__ shift, unsigned short* __restrict__ cat,
                          float* __restrict__ ush) {
    int i = blockIdx.x * 256 + threadIdx.x;
    if (i >= NN * 32) return;
    int n = i >> 5, j4 = (i & 31) * 4;
    ushort4 ub_in = *reinterpret_cast<const ushort4*>(nupd_bf + (size_t)n * 128 + j4);
    float4 sc = *reinterpret_cast<const float4*>(scale + j4);
    float4 sh = *reinterpret_cast<const float4*>(shift + j4);
    float4 uv;
    uv.x = bf2f(ub_in.x) * sc.x + sh.x;
    uv.y = bf2f(ub_in.y) * sc.y + sh.y;
    uv.z = bf2f(ub_in.z) * sc.z + sh.z;
    uv.w = bf2f(ub_in.w) * sc.w + sh.w;
    ushort4 ub;
    ub.x = f2bf(uv.x); ub.y = f2bf(uv.y); ub.z = f2bf(uv.z); ub.w = f2bf(uv.w);
    *reinterpret_cast<ushort4*>(cat + (size_t)n * 256 + 128 + j4) = ub;
    *reinterpret_cast<float4*>(ush + (size_t)n * 128 + j4) = uv;
}

// ---------------- GRU GEMM: S = cat @ Wc  (M x 256 x 512), MFMA, LDS-coalesced store ----------------
__global__ void __launch_bounds__(256) k_gru_mm(
        const unsigned short* __restrict__ cat, const unsigned short* __restrict__ WcT,
        float* __restrict__ S, int N) {
    __shared__ unsigned short ash[64][264];
    int n0 = blockIdx.x * 64;
    int g = blockIdx.y;
    int t = threadIdx.x;
    for (int q = t; q < 64 * 32; q += 256) {
        int r = q >> 5, c = q & 31;
        int n = n0 + r; if (n >= N) n = N - 1;
        *reinterpret_cast<uint4*>(&ash[r][c * 8]) =
            *reinterpret_cast<const uint4*>(cat + (size_t)n * 256 + c * 8);
    }
    __syncthreads();

    int wid = t >> 6, lane = t & 63;
    int wm = wid >> 1, wn = wid & 1;
    int lr = lane & 15, lg = lane >> 4;

    f32x4 acc[2][4];
#pragma unroll
    for (int m = 0; m < 2; ++m)
#pragma unroll
        for (int n = 0; n < 4; ++n) acc[m][n] = (f32x4){0.f, 0.f, 0.f, 0.f};

    const unsigned short* Wg = WcT + (size_t)g * 128 * 256;
#pragma unroll
    for (int ks = 0; ks < 8; ++ks) {
        int kb = ks * 32 + lg * 8;
        bf16x8 a0 = *reinterpret_cast<const bf16x8*>(&ash[wm * 32 + lr][kb]);
        bf16x8 a1 = *reinterpret_cast<const bf16x8*>(&ash[wm * 32 + 16 + lr][kb]);
        bf16x8 b[4];
#pragma unroll
        for (int n = 0; n < 4; ++n)
            b[n] = *reinterpret_cast<const bf16x8*>(Wg + (size_t)(wn * 64 + n * 16 + lr) * 256 + kb);
#pragma unroll
        for (int n = 0; n < 4; ++n) {
            acc[0][n] = __builtin_amdgcn_mfma_f32_16x16x32_bf16(a0, b[n], acc[0][n], 0, 0, 0);
            acc[1][n] = __builtin_amdgcn_mfma_f32_16x16x32_bf16(a1, b[n], acc[1][n], 0, 0, 0);
        }
    }

    __syncthreads();
    float* otf = reinterpret_cast<float*>(&ash[0][0]);   // [64][132] f32
#pragma unroll
    for (int n = 0; n < 4; ++n) {
        int col = wn * 64 + n * 16 + lr;
#pragma unroll
        for (int m = 0; m < 2; ++m) {
            int rowb = wm * 32 + m * 16 + lg * 4;
#pragma unroll
            for (int r = 0; r < 4; ++r)
                otf[(rowb + r) * 132 + col] = acc[m][n][r];
        }
    }
    __syncthreads();
    for (int q = t; q < 64 * 32; q += 256) {
        int r = q >> 5, c = q & 31;
        int row = n0 + r;
        if (row < N)
            *reinterpret_cast<float4*>(&S[(size_t)row * 512 + g * 128 + c * 4]) =
                *reinterpret_cast<const float4*>(&otf[r * 132 + c * 4]);
    }
}

// ---------------- GRU gates: sigmoid/tanh + combine ----------------
__global__ void __launch_bounds__(256) k_gru_gates(
        const float* __restrict__ S, const float* __restrict__ ush,
        const float* __restrict__ gbias, float* __restrict__ outp) {
    int t = threadIdx.x;
    int n = blockIdx.x * 2 + (t >> 7);
    int u = t & 127;
    const float* b0 = gbias;
    const float* b1 = gbias + 384;
    float s0 = S[(size_t)n * 512 + u];
    float s1 = S[(size_t)n * 512 + 128 + u];
    float xh = S[(size_t)n * 512 + 256 + u];
    float rh = S[(size_t)n * 512 + 384 + u];
    float zg = 1.f / (1.f + __expf(-(s0 + b0[u] + b1[u])));
    float rg = 1.f / (1.f + __expf(-(s1 + b0[128 + u] + b1[128 + u])));
    float hh = tanhf(xh + b0[256 + u] + rg * (rh + b1[256 + u]));
    float uv = ush[(size_t)n * 128 + u];
    outp[(size_t)n * 128 + u] = zg * uv + (1.f - zg) * hh;
}

// ---------------- launch ----------------
extern "C" void kernel_launch(void* const* d_in, const int* in_sizes, int n_in,
                              void* d_out, int out_size, void* d_ws, size_t ws_size,
                              hipStream_t stream) {
    const float* node    = (const float*)d_in[0];
    const float* eattr   = (const float*)d_in[1];
    const int*   eidx    = (const int*)d_in[2];
    const float* We      = (const float*)d_in[3];
    const float* be      = (const float*)d_in[4];
    const float* gamma_e = (const float*)d_in[5];
    const float* beta_e  = (const float*)d_in[6];
    const float* Wn      = (const float*)d_in[7];
    const float* bnb     = (const float*)d_in[8];
    const float* gamma_n = (const float*)d_in[9];
    const float* beta_n  = (const float*)d_in[10];
    const float* Watt    = (const float*)d_in[11];
    const float* batt    = (const float*)d_in[12];
    const float* aatt    = (const float*)d_in[13];
    const float* Wk      = (const float*)d_in[14];
    const float* Wr      = (const float*)d_in[15];
    const float* gbias   = (const float*)d_in[16];

    float* out_node = (float*)d_out;
    float* out_edge = out_node + (size_t)NN * UU;

    char* wp = (char*)d_ws;
    auto alloc = [&](size_t bytes) {
        void* p = (void*)wp;
        wp += (bytes + 255) / 256 * 256;
        return p;
    };
    unsigned char* zt8   = (unsigned char*)alloc((size_t)NN * 1024);       // z fp8 in (N,U,H)
    unsigned short* ebuf = (unsigned short*)alloc((size_t)EE * 128 * 2);
    float* s_src   = (float*)alloc((size_t)NN * 8 * 4);
    float* s_dst   = (float*)alloc((size_t)NN * 8 * 4);
    float* lsbuf   = (float*)alloc((size_t)EE * 8 * 4);
    int*   srcl    = (int*)alloc((size_t)EE * 4);
    float* part_e  = (float*)alloc((size_t)2500 * 256 * 4);
    float* part_n  = (float*)alloc((size_t)157 * 256 * 4);
    float* scale_e = (float*)alloc(512);
    float* shift_e = (float*)alloc(512);
    float* scale_n = (float*)alloc(512);
    float* shift_n = (float*)alloc(512);
    unsigned short* nupd_bf = (unsigned short*)alloc((size_t)NN * 128 * 2);
    float* ush     = (float*)alloc((size_t)NN * 128 * 4);
    float* Sbuf    = (float*)alloc((size_t)NN * 512 * 4);
    int*   cnt     = (int*)alloc((size_t)NN * 4);
    int*   offs    = (int*)alloc((size_t)(NN + 1) * 4);
    int*   cursor  = (int*)alloc((size_t)NN * 4);
    int*   elist   = (int*)alloc((size_t)EE * 4);
    int*   pos     = (int*)alloc((size_t)EE * 4);
    unsigned short* node_bf = (unsigned short*)alloc((size_t)NN * 128 * 2);
    unsigned short* WtE     = (unsigned short*)alloc((size_t)3 * 128 * 128 * 2);
    unsigned short* WtA     = (unsigned short*)alloc((size_t)8 * 128 * 128 * 2);
    unsigned short* WnT     = (unsigned short*)alloc((size_t)128 * 128 * 2);
    unsigned short* WcT     = (unsigned short*)alloc((size_t)512 * 256 * 2);
    unsigned short* cat     = (unsigned short*)alloc((size_t)NN * 256 * 2);
    unsigned short* p12     = (unsigned short*)alloc((size_t)NN * 256 * 2);

    hipMemsetAsync(cnt, 0, (size_t)NN * 4, stream);
    k_hist<<<(EE + 255) / 256, 256, 0, stream>>>(eidx, cnt, EE);
    k_scan<<<1, 1024, 0, stream>>>(cnt, offs, cursor, NN);
    k_scatter<<<(EE + 255) / 256, 256, 0, stream>>>(eidx, cursor, elist, pos, EE);

    k_prep<<<2530, 256, 0, stream>>>(node, node_bf, We, WtE, Wn, WnT, Watt, WtA, Wk, Wr, WcT);

    // node-side producers first (s_src needed by fused edge_final)
    k_z8<<<NN / 16, 256, 0, stream>>>(node_bf, WtA, batt, aatt, zt8, s_src, s_dst);
    k_node_mlp_mfma<<<(NN + 63) / 64, 256, 0, stream>>>(node_bf, WnT, bnb, nupd_bf, part_n, NN);

    // edge pipeline
    k_p12_mfma<<<dim3((NN + 63) / 64, 2), 256, 0, stream>>>(node_bf, WtE, p12, NN);
    k_pe_comb<<<EE / 64, 256, 0, stream>>>(eattr, WtE, be, p12, eidx, ebuf, part_e);
    k_bn_fin2<<<256, 256, 0, stream>>>(part_e, EE / 64, 1.f / (float)EE, gamma_e, beta_e, scale_e, shift_e,
                                       part_n, (NN + 63) / 64, 1.f / (float)NN, gamma_n, beta_n, scale_n, shift_n);
    k_edge_final<<<EE / 8, 256, 0, stream>>>(ebuf, scale_e, shift_e, aatt, eidx, pos, s_src,
                                             out_edge, lsbuf, srcl);

    // attention + GRU
    k_agg<<<NN / 4, 256, 0, stream>>>(zt8, lsbuf, srcl, s_dst, offs, cat);
    k_gru_pre<<<(NN * 32 + 255) / 256, 256, 0, stream>>>(nupd_bf, scale_n, shift_n, cat, ush);
    k_gru_mm<<<dim3((NN + 63) / 64, 4), 256, 0, stream>>>(cat, WcT, Sbuf, NN);
    k_gru_gates<<<NN / 2, 256, 0, stream>>>(Sbuf, ush, gbias, out_node);
}